// Round 8
// baseline (499.987 us; speedup 1.0000x reference)
//
#include <hip/hip_runtime.h>
#include <hip/hip_bf16.h>

typedef __attribute__((ext_vector_type(8))) short short8;
typedef __attribute__((ext_vector_type(8))) unsigned short u16x8;
typedef __attribute__((ext_vector_type(4))) float f32x4;

__device__ __forceinline__ unsigned short f2bf(float f) {
    unsigned int u = __float_as_uint(f);
    unsigned int r = (u + 0x7fffu + ((u >> 16) & 1u)) >> 16;   // RNE
    return (unsigned short)r;
}
__device__ __forceinline__ float bf2f(unsigned short u) {
    return __uint_as_float(((unsigned int)u) << 16);
}
__device__ __forceinline__ float4 min4(float4 a, float4 b) {
    return make_float4(fminf(a.x,b.x), fminf(a.y,b.y), fminf(a.z,b.z), fminf(a.w,b.w));
}
__device__ __forceinline__ float4 max4(float4 a, float4 b) {
    return make_float4(fmaxf(a.x,b.x), fmaxf(a.y,b.y), fmaxf(a.z,b.z), fmaxf(a.w,b.w));
}

// fallback-only: zero stat partials + convert W to bf16
__global__ __launch_bounds__(256) void prep_kernel(const float* __restrict__ W,
                                                   unsigned short* __restrict__ Wb,
                                                   float* __restrict__ partials) {
    const int i = blockIdx.x * 256 + threadIdx.x;
    if (i < 64 * 256) partials[i] = 0.f;
    if (i < 128 * 320) Wb[i] = f2bf(W[i]);
}

// zero partials + W->bf16 + x->bf16 (one launch)
__global__ __launch_bounds__(256) void prep_conv_kernel(
    const float* __restrict__ W, unsigned short* __restrict__ Wb,
    float* __restrict__ partials,
    const float* __restrict__ x, unsigned short* __restrict__ xb, long n8)
{
    const long g = blockIdx.x * 256L + threadIdx.x;
    if (g < 64 * 256) partials[g] = 0.f;
    if (g < 128 * 320) Wb[g] = f2bf(W[g]);
    const long stride = gridDim.x * 256L;
    for (long i = g; i < n8; i += stride) {
        const f32x4 a = __builtin_nontemporal_load(((const f32x4*)x) + i * 2);
        const f32x4 b = __builtin_nontemporal_load(((const f32x4*)x) + i * 2 + 1);
        u16x8 o;
        o[0] = f2bf(a[0]); o[1] = f2bf(a[1]); o[2] = f2bf(a[2]); o[3] = f2bf(a[3]);
        o[4] = f2bf(b[0]); o[5] = f2bf(b[1]); o[6] = f2bf(b[2]); o[7] = f2bf(b[3]);
        ((u16x8*)xb)[i] = o;
    }
}

// exact bf16 min/max pair via f32 (inputs bf16-exact -> results bf16-exact)
__device__ __forceinline__ void bfminmax(unsigned short a, unsigned short b,
                                         unsigned short& lo, unsigned short& hi) {
    const float fa = bf2f(a), fb = bf2f(b);
    lo = (unsigned short)(__float_as_uint(fminf(fa, fb)) >> 16);
    hi = (unsigned short)(__float_as_uint(fmaxf(fa, fb)) >> 16);
}

// ---- 16-row tile / 128-thread (2-wave) block: 16 blocks/CU, halved barrier
// convoy. LDS = 16*320*2 = 10240 B. Swizzle: chunk c8 at c8^((row&7)<<1).
__global__ __launch_bounds__(128, 8) void fused16_kernel(
    const unsigned short* __restrict__ xb, const int* __restrict__ nb,
    const unsigned short* __restrict__ Wb, unsigned short* __restrict__ hb,
    float* __restrict__ partials, int E)
{
    __shared__ __align__(16) unsigned short feat[16 * 320];

    const int tid = threadIdx.x;
    const int r0 = blockIdx.x * 16;
    const bool full = (r0 + 16 <= E);

    // ---- stage: thread (lr,o): row lr (0..15), 16B chunk o (0..7) per section
    {
        const int lr = tid >> 3;
        const int o  = tid & 7;
        const int gr = min(r0 + lr, E - 1);
        int4 nv = *(const int4*)(nb + (long)gr * 4);
        const int i0 = min(max(nv.x, 0), E - 1);
        const int i1 = min(max(nv.y, 0), E - 1);
        const int i2 = min(max(nv.z, 0), E - 1);
        const int i3 = min(max(nv.w, 0), E - 1);
        const int xr = (lr & 7) << 1;
        char* fb = (char*)feat + lr * 640;

        const u16x8 xv = *(const u16x8*)(xb + (long)gr * 64 + o * 8);
        const u16x8 av = *(const u16x8*)(xb + (long)i0 * 64 + o * 8);
        const u16x8 bv = *(const u16x8*)(xb + (long)i1 * 64 + o * 8);
        const u16x8 cv = *(const u16x8*)(xb + (long)i2 * 64 + o * 8);
        const u16x8 dv = *(const u16x8*)(xb + (long)i3 * 64 + o * 8);
        u16x8 lo1, hi1, lo2, hi2;
        #pragma unroll
        for (int e = 0; e < 8; ++e) {
            unsigned short l, h;
            bfminmax(av[e], bv[e], l, h); lo1[e] = l; hi1[e] = h;
            bfminmax(cv[e], dv[e], l, h); lo2[e] = l; hi2[e] = h;
        }
        const int c8 = o * 2;
        *(u16x8*)(fb + (((c8 +  0) ^ xr) << 3)) = xv;
        *(u16x8*)(fb + (((c8 + 16) ^ xr) << 3)) = lo1;
        *(u16x8*)(fb + (((c8 + 32) ^ xr) << 3)) = hi1;
        *(u16x8*)(fb + (((c8 + 48) ^ xr) << 3)) = lo2;
        *(u16x8*)(fb + (((c8 + 64) ^ xr) << 3)) = hi2;
    }
    __syncthreads();

    // ---- MFMA: wave w (0/1) owns cols [w*64, w*64+64) as 4 col-frags, rows 0..15
    const int lane = tid & 63;
    const int w    = tid >> 6;
    const int lr16 = lane & 15;
    const int lg   = lane >> 4;
    const int xr   = (lr16 & 7) << 1;
    const char* fbA = (const char*)feat + lr16 * 640;

    f32x4 acc[4];
    #pragma unroll
    for (int n = 0; n < 4; ++n) acc[n] = (f32x4){0.f, 0.f, 0.f, 0.f};

    // two col-pair passes to cap live B regs (VGPR <= 64 target)
    #pragma unroll
    for (int np = 0; np < 2; ++np) {
        const unsigned short* wb0 = Wb + ((w * 64 + np * 32 + lr16) * 320) + lg * 8;
        const unsigned short* wb1 = wb0 + 16 * 320;
        #pragma unroll
        for (int kk = 0; kk < 320; kk += 32) {
            const int off = ((((kk >> 2) + lg * 2) ^ xr) << 3);
            const short8 a  = *(const short8*)(fbA + off);
            const short8 b0 = *(const short8*)(wb0 + kk);
            const short8 b1 = *(const short8*)(wb1 + kk);
            acc[np*2+0] = __builtin_amdgcn_mfma_f32_16x16x32_bf16(a, b0, acc[np*2+0], 0, 0, 0);
            acc[np*2+1] = __builtin_amdgcn_mfma_f32_16x16x32_bf16(a, b1, acc[np*2+1], 0, 0, 0);
        }
    }

    // ---- stats (D layout: col = lane&15, row = (lane>>4)*4 + reg)
    #pragma unroll
    for (int n = 0; n < 4; ++n) {
        const int col = w * 64 + n * 16 + lr16;
        float s = 0.f, q = 0.f;
        if (full) {
            #pragma unroll
            for (int j = 0; j < 4; ++j) { const float v = acc[n][j]; s += v; q += v * v; }
        } else {
            #pragma unroll
            for (int j = 0; j < 4; ++j) {
                if (r0 + lg * 4 + j < E) { const float v = acc[n][j]; s += v; q += v * v; }
            }
        }
        s += __shfl_xor(s, 16); s += __shfl_xor(s, 32);
        q += __shfl_xor(q, 16); q += __shfl_xor(q, 32);
        if (lg == 0) {
            float* base = partials + (blockIdx.x & 63) * 256;
            atomicAdd(&base[col], s);
            atomicAdd(&base[128 + col], q);
        }
    }

    // ---- transpose through LDS (reuse feat), coalesced NT 16B stores
    __syncthreads();
    unsigned short* hsm = feat;          // 16 rows x pitch 132
    #pragma unroll
    for (int n = 0; n < 4; ++n) {
        const int col = w * 64 + n * 16 + lr16;
        #pragma unroll
        for (int j = 0; j < 4; ++j)
            hsm[(lg * 4 + j) * 132 + col] = f2bf(acc[n][j]);
    }
    __syncthreads();
    const int oct = tid & 15;
    const int lrr = tid >> 4;            // 0..7
    #pragma unroll
    for (int it = 0; it < 2; ++it) {
        const int r = lrr + it * 8;
        const int grow = r0 + r;
        if (full || grow < E)
            __builtin_nontemporal_store(
                *(const u16x8*)(hsm + r * 132 + oct * 8),
                (u16x8*)(hb + (long)grow * 128 + oct * 8));
    }
}

// ---- fallback non-persistent 32-row kernel (f32-x / f32-h paths)
template<bool XB, bool BF16H>
__global__ __launch_bounds__(256, 8) void fused_kernel(
    const float* __restrict__ x, const unsigned short* __restrict__ xb,
    const int* __restrict__ nb,
    const unsigned short* __restrict__ Wb, void* __restrict__ hout,
    float* __restrict__ partials, int E)
{
    __shared__ __align__(16) unsigned short feat[32 * 320];
    const int tid = threadIdx.x;
    const int r0 = blockIdx.x * 32;
    {
        const int lr = tid >> 3;
        const int o  = tid & 7;
        const int gr = min(r0 + lr, E - 1);
        int4 nv = *(const int4*)(nb + (long)gr * 4);
        const int i0 = min(max(nv.x, 0), E - 1);
        const int i1 = min(max(nv.y, 0), E - 1);
        const int i2 = min(max(nv.z, 0), E - 1);
        const int i3 = min(max(nv.w, 0), E - 1);
        const int xr = (lr & 7) << 1;
        char* fb = (char*)feat + lr * 640;
        if (XB) {
            const u16x8 xv = *(const u16x8*)(xb + (long)gr * 64 + o * 8);
            const u16x8 av = *(const u16x8*)(xb + (long)i0 * 64 + o * 8);
            const u16x8 bv = *(const u16x8*)(xb + (long)i1 * 64 + o * 8);
            const u16x8 cv = *(const u16x8*)(xb + (long)i2 * 64 + o * 8);
            const u16x8 dv = *(const u16x8*)(xb + (long)i3 * 64 + o * 8);
            u16x8 lo1, hi1, lo2, hi2;
            #pragma unroll
            for (int e = 0; e < 8; ++e) {
                unsigned short l, h;
                bfminmax(av[e], bv[e], l, h); lo1[e] = l; hi1[e] = h;
                bfminmax(cv[e], dv[e], l, h); lo2[e] = l; hi2[e] = h;
            }
            const int c8 = o * 2;
            *(u16x8*)(fb + (((c8 +  0) ^ xr) << 3)) = xv;
            *(u16x8*)(fb + (((c8 + 16) ^ xr) << 3)) = lo1;
            *(u16x8*)(fb + (((c8 + 32) ^ xr) << 3)) = hi1;
            *(u16x8*)(fb + (((c8 + 48) ^ xr) << 3)) = lo2;
            *(u16x8*)(fb + (((c8 + 64) ^ xr) << 3)) = hi2;
        } else {
            #pragma unroll
            for (int c = 0; c < 2; ++c) {
                const int col = o * 8 + c * 4;
                const float4 xvf = *(const float4*)(x + (long)gr * 64 + col);
                const float4 avf = *(const float4*)(x + (long)i0 * 64 + col);
                const float4 bvf = *(const float4*)(x + (long)i1 * 64 + col);
                const float4 cvf = *(const float4*)(x + (long)i2 * 64 + col);
                const float4 dvf = *(const float4*)(x + (long)i3 * 64 + col);
                const float4 vals[5] = { xvf, min4(avf,bvf), max4(avf,bvf),
                                         min4(cvf,dvf), max4(cvf,dvf) };
                #pragma unroll
                for (int s = 0; s < 5; ++s) {
                    const int c8 = s * 16 + o * 2 + c;
                    ushort4 p;
                    p.x = f2bf(vals[s].x); p.y = f2bf(vals[s].y);
                    p.z = f2bf(vals[s].z); p.w = f2bf(vals[s].w);
                    *(ushort4*)(fb + ((c8 ^ xr) << 3)) = p;
                }
            }
        }
    }
    __syncthreads();
    const int lane = tid & 63;
    const int wid  = tid >> 6;
    const int lr16 = lane & 15;
    const int lg   = lane >> 4;
    const int xr   = (lr16 & 7) << 1;
    f32x4 acc[2][2];
    #pragma unroll
    for (int m = 0; m < 2; ++m)
        #pragma unroll
        for (int n = 0; n < 2; ++n)
            acc[m][n] = (f32x4){0.f, 0.f, 0.f, 0.f};
    const char* fb0 = (const char*)feat + lr16 * 640;
    const char* fb1 = (const char*)feat + (16 + lr16) * 640;
    const unsigned short* wb = Wb + (wid * 32 + lr16) * 320 + lg * 8;
    #pragma unroll
    for (int kk = 0; kk < 320; kk += 32) {
        const int c8  = (kk >> 2) + lg * 2;
        const int off = (c8 ^ xr) << 3;
        const short8 a0 = *(const short8*)(fb0 + off);
        const short8 a1 = *(const short8*)(fb1 + off);
        const short8 b0 = *(const short8*)(wb + kk);
        const short8 b1 = *(const short8*)(wb + 16 * 320 + kk);
        acc[0][0] = __builtin_amdgcn_mfma_f32_16x16x32_bf16(a0, b0, acc[0][0], 0, 0, 0);
        acc[0][1] = __builtin_amdgcn_mfma_f32_16x16x32_bf16(a0, b1, acc[0][1], 0, 0, 0);
        acc[1][0] = __builtin_amdgcn_mfma_f32_16x16x32_bf16(a1, b0, acc[1][0], 0, 0, 0);
        acc[1][1] = __builtin_amdgcn_mfma_f32_16x16x32_bf16(a1, b1, acc[1][1], 0, 0, 0);
    }
    #pragma unroll
    for (int n = 0; n < 2; ++n) {
        const int col = wid * 32 + n * 16 + lr16;
        float s = 0.f, q = 0.f;
        #pragma unroll
        for (int m = 0; m < 2; ++m) {
            const int rbase = r0 + m * 16 + lg * 4;
            #pragma unroll
            for (int j = 0; j < 4; ++j) {
                if (rbase + j < E) {
                    const float v = acc[m][n][j];
                    s += v; q += v * v;
                }
            }
        }
        s += __shfl_xor(s, 16); s += __shfl_xor(s, 32);
        q += __shfl_xor(q, 16); q += __shfl_xor(q, 32);
        if (lg == 0) {
            float* base = partials + (blockIdx.x & 63) * 256;
            atomicAdd(&base[col], s);
            atomicAdd(&base[128 + col], q);
        }
    }
    if (BF16H) {
        __syncthreads();
        unsigned short* hsm = feat;
        #pragma unroll
        for (int m = 0; m < 2; ++m) {
            const int rb = m * 16 + lg * 4;
            #pragma unroll
            for (int n = 0; n < 2; ++n) {
                const int col = wid * 32 + n * 16 + lr16;
                #pragma unroll
                for (int j = 0; j < 4; ++j)
                    hsm[(rb + j) * 132 + col] = f2bf(acc[m][n][j]);
            }
        }
        __syncthreads();
        unsigned short* hbp = (unsigned short*)hout;
        const int oct = tid & 15;
        const int lrr = tid >> 4;
        #pragma unroll
        for (int it = 0; it < 2; ++it) {
            const int r = lrr + it * 16;
            const int grow = r0 + r;
            if (grow < E)
                __builtin_nontemporal_store(
                    *(const u16x8*)(hsm + r * 132 + oct * 8),
                    (u16x8*)(hbp + (long)grow * 128 + oct * 8));
        }
    } else {
        float* hf = (float*)hout;
        #pragma unroll
        for (int n = 0; n < 2; ++n) {
            const int col = wid * 32 + n * 16 + lr16;
            #pragma unroll
            for (int m = 0; m < 2; ++m) {
                const int rbase = r0 + m * 16 + lg * 4;
                #pragma unroll
                for (int j = 0; j < 4; ++j) {
                    const int grow = rbase + j;
                    if (grow < E)
                        __builtin_nontemporal_store(acc[m][n][j],
                            hf + (long)grow * 128 + col);
                }
            }
        }
    }
}

__global__ void finalize_kernel(const float* __restrict__ partials,
                                const float* __restrict__ gamma,
                                const float* __restrict__ beta,
                                float* __restrict__ sb, int E)
{
    const int c = threadIdx.x;   // 0..127
    float s = 0.f, q = 0.f;
    for (int b = 0; b < 64; ++b) {
        s += partials[b * 256 + c];
        q += partials[b * 256 + 128 + c];
    }
    const float inv  = 1.0f / (float)E;
    const float mean = s * inv;
    const float var  = fmaxf(q * inv - mean * mean, 0.f);
    const float sc   = gamma[c] / sqrtf(var + 1e-5f);
    sb[c]       = sc;
    sb[128 + c] = beta[c] - mean * sc;
}

// bf16-h variant: 32 B/thread/iter (2 u16x8 NT reads, 4 f32x4 NT writes)
__global__ __launch_bounds__(256) void bn_relu_bf16_kernel(
    const unsigned short* __restrict__ hb, const float* __restrict__ sb,
    float* __restrict__ out, long n16)
{
    __shared__ float s_s[128], s_b[128];
    if (threadIdx.x < 128) {
        s_s[threadIdx.x] = sb[threadIdx.x];
        s_b[threadIdx.x] = sb[128 + threadIdx.x];
    }
    __syncthreads();
    long i = blockIdx.x * 256L + threadIdx.x;
    const long stride = gridDim.x * 256L;
    for (; i < n16; i += stride) {
        const u16x8 v0 = __builtin_nontemporal_load(((const u16x8*)hb) + i * 2);
        const u16x8 v1 = __builtin_nontemporal_load(((const u16x8*)hb) + i * 2 + 1);
        const int c0 = ((int)i & 7) << 4;
        f32x4 o0, o1, o2, o3;
        #pragma unroll
        for (int k = 0; k < 4; ++k) {
            o0[k] = fmaxf(fmaf(bf2f(v0[k]),     s_s[c0+k],      s_b[c0+k]), 0.f);
            o1[k] = fmaxf(fmaf(bf2f(v0[k+4]),   s_s[c0+4+k],    s_b[c0+4+k]), 0.f);
            o2[k] = fmaxf(fmaf(bf2f(v1[k]),     s_s[c0+8+k],    s_b[c0+8+k]), 0.f);
            o3[k] = fmaxf(fmaf(bf2f(v1[k+4]),   s_s[c0+12+k],   s_b[c0+12+k]), 0.f);
        }
        __builtin_nontemporal_store(o0, ((f32x4*)out) + i * 4);
        __builtin_nontemporal_store(o1, ((f32x4*)out) + i * 4 + 1);
        __builtin_nontemporal_store(o2, ((f32x4*)out) + i * 4 + 2);
        __builtin_nontemporal_store(o3, ((f32x4*)out) + i * 4 + 3);
    }
}

// f32 fallback: in-place on d_out
__global__ __launch_bounds__(256) void bn_relu_kernel(float* __restrict__ h,
                                                      const float* __restrict__ sb, long n4)
{
    __shared__ float s_s[128], s_b[128];
    if (threadIdx.x < 128) {
        s_s[threadIdx.x] = sb[threadIdx.x];
        s_b[threadIdx.x] = sb[128 + threadIdx.x];
    }
    __syncthreads();
    long i = blockIdx.x * 256L + threadIdx.x;
    const long stride = gridDim.x * 256L;
    for (; i < n4; i += stride) {
        f32x4 v = __builtin_nontemporal_load(((const f32x4*)h) + i);
        const int c = ((int)i * 4) & 127;
        v[0] = fmaxf(fmaf(v[0], s_s[c + 0], s_b[c + 0]), 0.f);
        v[1] = fmaxf(fmaf(v[1], s_s[c + 1], s_b[c + 1]), 0.f);
        v[2] = fmaxf(fmaf(v[2], s_s[c + 2], s_b[c + 2]), 0.f);
        v[3] = fmaxf(fmaf(v[3], s_s[c + 3], s_b[c + 3]), 0.f);
        __builtin_nontemporal_store(v, ((f32x4*)h) + i);
    }
}

extern "C" void kernel_launch(void* const* d_in, const int* in_sizes, int n_in,
                              void* d_out, int out_size, void* d_ws, size_t ws_size,
                              hipStream_t stream)
{
    const float* x     = (const float*)d_in[0];
    const int*   nb    = (const int*)d_in[1];
    const float* W     = (const float*)d_in[2];
    const float* gamma = (const float*)d_in[3];
    const float* beta  = (const float*)d_in[4];
    float* out = (float*)d_out;

    const int E = in_sizes[0] / 64;

    // ws layout: Wb 80K | partials 64K | sb 1K | xb (E*128 B) | hb (E*256 B)
    char* ws = (char*)d_ws;
    unsigned short* Wb       = (unsigned short*)ws;
    float*          partials = (float*)(ws + 81920);
    float*          sb       = (float*)(ws + 81920 + 65536);
    unsigned short* xb       = (unsigned short*)(ws + 148480);
    const size_t xb_end = 148480 + (size_t)E * 128;
    unsigned short* hb       = (unsigned short*)(ws + xb_end);
    const bool have_xb = (ws_size >= xb_end);
    const bool have_hb = (ws_size >= xb_end + (size_t)E * 256);

    if (have_xb)
        prep_conv_kernel<<<2048, 256, 0, stream>>>(W, Wb, partials, x, xb, (long)E * 8);
    else
        prep_kernel<<<160, 256, 0, stream>>>(W, Wb, partials);

    if (have_xb && have_hb) {
        const int T16 = (E + 15) / 16;
        fused16_kernel<<<T16, 128, 0, stream>>>(xb, nb, Wb, hb, partials, E);
    } else {
        const int T = (E + 31) / 32;
        if (have_xb)
            fused_kernel<true,  false><<<T, 256, 0, stream>>>(x, xb, nb, Wb, out, partials, E);
        else if (have_hb)
            fused_kernel<false, true ><<<T, 256, 0, stream>>>(x, xb, nb, Wb, hb, partials, E);
        else
            fused_kernel<false, false><<<T, 256, 0, stream>>>(x, xb, nb, Wb, out, partials, E);
    }

    finalize_kernel<<<1, 128, 0, stream>>>(partials, gamma, beta, sb, E);

    if (have_hb)
        bn_relu_bf16_kernel<<<4096, 256, 0, stream>>>(hb, sb, out, (long)E * 8);
    else
        bn_relu_kernel<<<2048, 256, 0, stream>>>(out, sb, (long)E * 32);
}

// Round 9
// 367.810 us; speedup vs baseline: 1.3594x; 1.3594x over previous
//
#include <hip/hip_runtime.h>
#include <hip/hip_bf16.h>

typedef __attribute__((ext_vector_type(8))) short short8;
typedef __attribute__((ext_vector_type(8))) unsigned short u16x8;
typedef __attribute__((ext_vector_type(4))) float f32x4;

__device__ __forceinline__ unsigned short f2bf(float f) {
    unsigned int u = __float_as_uint(f);
    unsigned int r = (u + 0x7fffu + ((u >> 16) & 1u)) >> 16;   // RNE
    return (unsigned short)r;
}
__device__ __forceinline__ float bf2f(unsigned short u) {
    return __uint_as_float(((unsigned int)u) << 16);
}
__device__ __forceinline__ float4 min4(float4 a, float4 b) {
    return make_float4(fminf(a.x,b.x), fminf(a.y,b.y), fminf(a.z,b.z), fminf(a.w,b.w));
}
__device__ __forceinline__ float4 max4(float4 a, float4 b) {
    return make_float4(fmaxf(a.x,b.x), fmaxf(a.y,b.y), fmaxf(a.z,b.z), fmaxf(a.w,b.w));
}

// fallback-only: zero stat partials + convert W to bf16
__global__ __launch_bounds__(256) void prep_kernel(const float* __restrict__ W,
                                                   unsigned short* __restrict__ Wb,
                                                   float* __restrict__ partials) {
    const int i = blockIdx.x * 256 + threadIdx.x;
    if (i < 64 * 256) partials[i] = 0.f;
    if (i < 128 * 320) Wb[i] = f2bf(W[i]);
}

// zero partials + W->bf16 + x->bf16 (one launch)
__global__ __launch_bounds__(256) void prep_conv_kernel(
    const float* __restrict__ W, unsigned short* __restrict__ Wb,
    float* __restrict__ partials,
    const float* __restrict__ x, unsigned short* __restrict__ xb, long n8)
{
    const long g = blockIdx.x * 256L + threadIdx.x;
    if (g < 64 * 256) partials[g] = 0.f;
    if (g < 128 * 320) Wb[g] = f2bf(W[g]);
    const long stride = gridDim.x * 256L;
    for (long i = g; i < n8; i += stride) {
        const f32x4 a = __builtin_nontemporal_load(((const f32x4*)x) + i * 2);
        const f32x4 b = __builtin_nontemporal_load(((const f32x4*)x) + i * 2 + 1);
        u16x8 o;
        o[0] = f2bf(a[0]); o[1] = f2bf(a[1]); o[2] = f2bf(a[2]); o[3] = f2bf(a[3]);
        o[4] = f2bf(b[0]); o[5] = f2bf(b[1]); o[6] = f2bf(b[2]); o[7] = f2bf(b[3]);
        ((u16x8*)xb)[i] = o;
    }
}

// One block: 32 rows x 128 output channels. K = 320. LDS = 32*320*2 = 20480 B
// -> 8 blocks/CU. XOR swizzle on 8B chunks: chunk c8 stored at c8 ^ ((row&7)<<1).
// k-loop uses depth-1 B prefetch (tests the B-load-serialization hypothesis).
template<bool XB, bool BF16H>
__global__ __launch_bounds__(256, 8) void fused_kernel(
    const float* __restrict__ x, const unsigned short* __restrict__ xb,
    const int* __restrict__ nb,
    const unsigned short* __restrict__ Wb, void* __restrict__ hout,
    float* __restrict__ partials, int E)
{
    __shared__ __align__(16) unsigned short feat[32 * 320];

    const int tid = threadIdx.x;
    const int r0 = blockIdx.x * 32;

    // ---- stage feat tile [x | min01 | max01 | min23 | max23] as bf16, swizzled
    {
        const int lr = tid >> 3;            // local row 0..31
        const int o  = tid & 7;             // 16B chunk within a 64-col section
        const int gr = min(r0 + lr, E - 1);
        int4 nv = *(const int4*)(nb + (long)gr * 4);
        const int i0 = min(max(nv.x, 0), E - 1);
        const int i1 = min(max(nv.y, 0), E - 1);
        const int i2 = min(max(nv.z, 0), E - 1);
        const int i3 = min(max(nv.w, 0), E - 1);
        const int xr = (lr & 7) << 1;
        char* fb = (char*)feat + lr * 640;

        if (XB) {
            const u16x8 xv = *(const u16x8*)(xb + (long)gr * 64 + o * 8);
            const u16x8 av = *(const u16x8*)(xb + (long)i0 * 64 + o * 8);
            const u16x8 bv = *(const u16x8*)(xb + (long)i1 * 64 + o * 8);
            const u16x8 cv = *(const u16x8*)(xb + (long)i2 * 64 + o * 8);
            const u16x8 dv = *(const u16x8*)(xb + (long)i3 * 64 + o * 8);
            u16x8 lo1, hi1, lo2, hi2;
            #pragma unroll
            for (int e = 0; e < 8; ++e) {
                const bool t1 = bf2f(av[e]) < bf2f(bv[e]);
                lo1[e] = t1 ? av[e] : bv[e];
                hi1[e] = t1 ? bv[e] : av[e];
                const bool t2 = bf2f(cv[e]) < bf2f(dv[e]);
                lo2[e] = t2 ? cv[e] : dv[e];
                hi2[e] = t2 ? dv[e] : cv[e];
            }
            const int c8 = o * 2;
            *(u16x8*)(fb + (((c8 +  0) ^ xr) << 3)) = xv;
            *(u16x8*)(fb + (((c8 + 16) ^ xr) << 3)) = lo1;
            *(u16x8*)(fb + (((c8 + 32) ^ xr) << 3)) = hi1;
            *(u16x8*)(fb + (((c8 + 48) ^ xr) << 3)) = lo2;
            *(u16x8*)(fb + (((c8 + 64) ^ xr) << 3)) = hi2;
        } else {
            #pragma unroll
            for (int c = 0; c < 2; ++c) {
                const int col = o * 8 + c * 4;
                const float4 xvf = *(const float4*)(x + (long)gr * 64 + col);
                const float4 avf = *(const float4*)(x + (long)i0 * 64 + col);
                const float4 bvf = *(const float4*)(x + (long)i1 * 64 + col);
                const float4 cvf = *(const float4*)(x + (long)i2 * 64 + col);
                const float4 dvf = *(const float4*)(x + (long)i3 * 64 + col);
                const float4 vals[5] = { xvf, min4(avf,bvf), max4(avf,bvf),
                                         min4(cvf,dvf), max4(cvf,dvf) };
                #pragma unroll
                for (int s = 0; s < 5; ++s) {
                    const int c8 = s * 16 + o * 2 + c;
                    ushort4 p;
                    p.x = f2bf(vals[s].x); p.y = f2bf(vals[s].y);
                    p.z = f2bf(vals[s].z); p.w = f2bf(vals[s].w);
                    *(ushort4*)(fb + ((c8 ^ xr) << 3)) = p;
                }
            }
        }
    }
    __syncthreads();

    // ---- MFMA: 4 waves; wave w owns cols [w*32, w*32+32). Each: 32 rows x 32 cols.
    const int lane = tid & 63;
    const int wid  = tid >> 6;
    const int lr16 = lane & 15;
    const int lg   = lane >> 4;             // 0..3
    const int xr   = (lr16 & 7) << 1;

    f32x4 acc[2][2];
    #pragma unroll
    for (int m = 0; m < 2; ++m)
        #pragma unroll
        for (int n = 0; n < 2; ++n)
            acc[m][n] = (f32x4){0.f, 0.f, 0.f, 0.f};

    const char* fb0 = (const char*)feat + lr16 * 640;
    const char* fb1 = (const char*)feat + (16 + lr16) * 640;
    const unsigned short* wb = Wb + (wid * 32 + lr16) * 320 + lg * 8;

    short8 b0 = *(const short8*)(wb);
    short8 b1 = *(const short8*)(wb + 16 * 320);
    #pragma unroll
    for (int kk = 0; kk < 320; kk += 32) {
        short8 b0n = b0, b1n = b1;
        if (kk + 32 < 320) {                    // compile-time guard (full unroll)
            b0n = *(const short8*)(wb + kk + 32);
            b1n = *(const short8*)(wb + 16 * 320 + kk + 32);
        }
        const int c8  = (kk >> 2) + lg * 2;
        const int off = (c8 ^ xr) << 3;
        const short8 a0 = *(const short8*)(fb0 + off);
        const short8 a1 = *(const short8*)(fb1 + off);
        acc[0][0] = __builtin_amdgcn_mfma_f32_16x16x32_bf16(a0, b0, acc[0][0], 0, 0, 0);
        acc[0][1] = __builtin_amdgcn_mfma_f32_16x16x32_bf16(a0, b1, acc[0][1], 0, 0, 0);
        acc[1][0] = __builtin_amdgcn_mfma_f32_16x16x32_bf16(a1, b0, acc[1][0], 0, 0, 0);
        acc[1][1] = __builtin_amdgcn_mfma_f32_16x16x32_bf16(a1, b1, acc[1][1], 0, 0, 0);
        b0 = b0n; b1 = b1n;
    }

    // ---- stats from regs (D layout: col = lane&15, row = (lane>>4)*4 + reg)
    #pragma unroll
    for (int n = 0; n < 2; ++n) {
        const int col = wid * 32 + n * 16 + lr16;
        float s = 0.f, q = 0.f;
        #pragma unroll
        for (int m = 0; m < 2; ++m) {
            const int rbase = r0 + m * 16 + lg * 4;
            #pragma unroll
            for (int j = 0; j < 4; ++j) {
                if (rbase + j < E) {
                    const float v = acc[m][n][j];
                    s += v;
                    q += v * v;
                }
            }
        }
        s += __shfl_xor(s, 16); s += __shfl_xor(s, 32);
        q += __shfl_xor(q, 16); q += __shfl_xor(q, 32);
        if (lg == 0) {
            float* base = partials + (blockIdx.x & 63) * 256;
            atomicAdd(&base[col], s);
            atomicAdd(&base[128 + col], q);
        }
    }

    if (BF16H) {
        // ---- transpose acc through LDS (reuse feat), then coalesced NT 16B stores
        __syncthreads();                      // all waves done reading feat
        unsigned short* hsm = feat;           // 32 rows x pitch 132
        #pragma unroll
        for (int m = 0; m < 2; ++m) {
            const int rb = m * 16 + lg * 4;
            #pragma unroll
            for (int n = 0; n < 2; ++n) {
                const int col = wid * 32 + n * 16 + lr16;
                #pragma unroll
                for (int j = 0; j < 4; ++j)
                    hsm[(rb + j) * 132 + col] = f2bf(acc[m][n][j]);
            }
        }
        __syncthreads();
        unsigned short* hb = (unsigned short*)hout;
        const int oct = tid & 15;             // 8-col chunk
        const int lrr = tid >> 4;             // 0..15
        #pragma unroll
        for (int it = 0; it < 2; ++it) {
            const int r = lrr + it * 16;
            const int grow = r0 + r;
            if (grow < E)
                __builtin_nontemporal_store(
                    *(const u16x8*)(hsm + r * 132 + oct * 8),
                    (u16x8*)(hb + (long)grow * 128 + oct * 8));
        }
    } else {
        float* hf = (float*)hout;
        #pragma unroll
        for (int n = 0; n < 2; ++n) {
            const int col = wid * 32 + n * 16 + lr16;
            #pragma unroll
            for (int m = 0; m < 2; ++m) {
                const int rbase = r0 + m * 16 + lg * 4;
                #pragma unroll
                for (int j = 0; j < 4; ++j) {
                    const int grow = rbase + j;
                    if (grow < E)
                        __builtin_nontemporal_store(acc[m][n][j],
                            hf + (long)grow * 128 + col);
                }
            }
        }
    }
}

__global__ void finalize_kernel(const float* __restrict__ partials,
                                const float* __restrict__ gamma,
                                const float* __restrict__ beta,
                                float* __restrict__ sb, int E)
{
    const int c = threadIdx.x;   // 0..127
    float s = 0.f, q = 0.f;
    for (int b = 0; b < 64; ++b) {
        s += partials[b * 256 + c];
        q += partials[b * 256 + 128 + c];
    }
    const float inv  = 1.0f / (float)E;
    const float mean = s * inv;
    const float var  = fmaxf(q * inv - mean * mean, 0.f);
    const float sc   = gamma[c] / sqrtf(var + 1e-5f);
    sb[c]       = sc;
    sb[128 + c] = beta[c] - mean * sc;
}

// bf16-h variant: 32 B/thread/iter (2 u16x8 NT reads, 4 f32x4 NT writes)
__global__ __launch_bounds__(256) void bn_relu_bf16_kernel(
    const unsigned short* __restrict__ hb, const float* __restrict__ sb,
    float* __restrict__ out, long n16)
{
    __shared__ float s_s[128], s_b[128];
    if (threadIdx.x < 128) {
        s_s[threadIdx.x] = sb[threadIdx.x];
        s_b[threadIdx.x] = sb[128 + threadIdx.x];
    }
    __syncthreads();
    long i = blockIdx.x * 256L + threadIdx.x;
    const long stride = gridDim.x * 256L;
    for (; i < n16; i += stride) {
        const u16x8 v0 = __builtin_nontemporal_load(((const u16x8*)hb) + i * 2);
        const u16x8 v1 = __builtin_nontemporal_load(((const u16x8*)hb) + i * 2 + 1);
        const int c0 = ((int)i & 7) << 4;
        f32x4 o0, o1, o2, o3;
        #pragma unroll
        for (int k = 0; k < 4; ++k) {
            o0[k] = fmaxf(fmaf(bf2f(v0[k]),   s_s[c0+k],    s_b[c0+k]), 0.f);
            o1[k] = fmaxf(fmaf(bf2f(v0[k+4]), s_s[c0+4+k],  s_b[c0+4+k]), 0.f);
            o2[k] = fmaxf(fmaf(bf2f(v1[k]),   s_s[c0+8+k],  s_b[c0+8+k]), 0.f);
            o3[k] = fmaxf(fmaf(bf2f(v1[k+4]), s_s[c0+12+k], s_b[c0+12+k]), 0.f);
        }
        __builtin_nontemporal_store(o0, ((f32x4*)out) + i * 4);
        __builtin_nontemporal_store(o1, ((f32x4*)out) + i * 4 + 1);
        __builtin_nontemporal_store(o2, ((f32x4*)out) + i * 4 + 2);
        __builtin_nontemporal_store(o3, ((f32x4*)out) + i * 4 + 3);
    }
}

// f32 fallback: in-place on d_out
__global__ __launch_bounds__(256) void bn_relu_kernel(float* __restrict__ h,
                                                      const float* __restrict__ sb, long n4)
{
    __shared__ float s_s[128], s_b[128];
    if (threadIdx.x < 128) {
        s_s[threadIdx.x] = sb[threadIdx.x];
        s_b[threadIdx.x] = sb[128 + threadIdx.x];
    }
    __syncthreads();
    long i = blockIdx.x * 256L + threadIdx.x;
    const long stride = gridDim.x * 256L;
    for (; i < n4; i += stride) {
        f32x4 v = __builtin_nontemporal_load(((const f32x4*)h) + i);
        const int c = ((int)i * 4) & 127;
        v[0] = fmaxf(fmaf(v[0], s_s[c + 0], s_b[c + 0]), 0.f);
        v[1] = fmaxf(fmaf(v[1], s_s[c + 1], s_b[c + 1]), 0.f);
        v[2] = fmaxf(fmaf(v[2], s_s[c + 2], s_b[c + 2]), 0.f);
        v[3] = fmaxf(fmaf(v[3], s_s[c + 3], s_b[c + 3]), 0.f);
        __builtin_nontemporal_store(v, ((f32x4*)h) + i);
    }
}

extern "C" void kernel_launch(void* const* d_in, const int* in_sizes, int n_in,
                              void* d_out, int out_size, void* d_ws, size_t ws_size,
                              hipStream_t stream)
{
    const float* x     = (const float*)d_in[0];
    const int*   nb    = (const int*)d_in[1];
    const float* W     = (const float*)d_in[2];
    const float* gamma = (const float*)d_in[3];
    const float* beta  = (const float*)d_in[4];
    float* out = (float*)d_out;

    const int E = in_sizes[0] / 64;

    // ws layout: Wb 80K | partials 64K | sb 1K | xb (E*128 B) | hb (E*256 B)
    char* ws = (char*)d_ws;
    unsigned short* Wb       = (unsigned short*)ws;
    float*          partials = (float*)(ws + 81920);
    float*          sb       = (float*)(ws + 81920 + 65536);
    unsigned short* xb       = (unsigned short*)(ws + 148480);
    const size_t xb_end = 148480 + (size_t)E * 128;
    unsigned short* hb       = (unsigned short*)(ws + xb_end);
    const bool have_xb = (ws_size >= xb_end);
    const bool have_hb = (ws_size >= xb_end + (size_t)E * 256);

    if (have_xb)
        prep_conv_kernel<<<2048, 256, 0, stream>>>(W, Wb, partials, x, xb, (long)E * 8);
    else
        prep_kernel<<<160, 256, 0, stream>>>(W, Wb, partials);

    const int T = (E + 31) / 32;
    void* hdst = have_hb ? (void*)hb : (void*)out;
    if (have_xb && have_hb)
        fused_kernel<true,  true ><<<T, 256, 0, stream>>>(x, xb, nb, Wb, hdst, partials, E);
    else if (have_xb)
        fused_kernel<true,  false><<<T, 256, 0, stream>>>(x, xb, nb, Wb, hdst, partials, E);
    else if (have_hb)
        fused_kernel<false, true ><<<T, 256, 0, stream>>>(x, xb, nb, Wb, hdst, partials, E);
    else
        fused_kernel<false, false><<<T, 256, 0, stream>>>(x, xb, nb, Wb, hdst, partials, E);

    finalize_kernel<<<1, 128, 0, stream>>>(partials, gamma, beta, sb, E);

    if (have_hb)
        bn_relu_bf16_kernel<<<4096, 256, 0, stream>>>(hb, sb, out, (long)E * 8);
    else
        bn_relu_kernel<<<2048, 256, 0, stream>>>(out, sb, (long)E * 32);
}

// Round 10
// 304.630 us; speedup vs baseline: 1.6413x; 1.2074x over previous
//
#include <hip/hip_runtime.h>
#include <hip/hip_bf16.h>

typedef __attribute__((ext_vector_type(8))) short short8;
typedef __attribute__((ext_vector_type(8))) unsigned short u16x8;
typedef __attribute__((ext_vector_type(4))) unsigned short u16x4;
typedef __attribute__((ext_vector_type(4))) float f32x4;

__device__ __forceinline__ unsigned short f2bf(float f) {
    unsigned int u = __float_as_uint(f);
    unsigned int r = (u + 0x7fffu + ((u >> 16) & 1u)) >> 16;   // RNE
    return (unsigned short)r;
}
__device__ __forceinline__ float bf2f(unsigned short u) {
    return __uint_as_float(((unsigned int)u) << 16);
}
__device__ __forceinline__ float4 min4(float4 a, float4 b) {
    return make_float4(fminf(a.x,b.x), fminf(a.y,b.y), fminf(a.z,b.z), fminf(a.w,b.w));
}
__device__ __forceinline__ float4 max4(float4 a, float4 b) {
    return make_float4(fmaxf(a.x,b.x), fmaxf(a.y,b.y), fmaxf(a.z,b.z), fmaxf(a.w,b.w));
}

// fallback-only: zero stat partials + convert W to bf16
__global__ __launch_bounds__(256) void prep_kernel(const float* __restrict__ W,
                                                   unsigned short* __restrict__ Wb,
                                                   float* __restrict__ partials) {
    const int i = blockIdx.x * 256 + threadIdx.x;
    if (i < 64 * 256) partials[i] = 0.f;
    if (i < 128 * 320) Wb[i] = f2bf(W[i]);
}

// zero partials + W->bf16 + x->bf16 (one launch)
__global__ __launch_bounds__(256) void prep_conv_kernel(
    const float* __restrict__ W, unsigned short* __restrict__ Wb,
    float* __restrict__ partials,
    const float* __restrict__ x, unsigned short* __restrict__ xb, long n8)
{
    const long g = blockIdx.x * 256L + threadIdx.x;
    if (g < 64 * 256) partials[g] = 0.f;
    if (g < 128 * 320) Wb[g] = f2bf(W[g]);
    const long stride = gridDim.x * 256L;
    for (long i = g; i < n8; i += stride) {
        const f32x4 a = __builtin_nontemporal_load(((const f32x4*)x) + i * 2);
        const f32x4 b = __builtin_nontemporal_load(((const f32x4*)x) + i * 2 + 1);
        u16x8 o;
        o[0] = f2bf(a[0]); o[1] = f2bf(a[1]); o[2] = f2bf(a[2]); o[3] = f2bf(a[3]);
        o[4] = f2bf(b[0]); o[5] = f2bf(b[1]); o[6] = f2bf(b[2]); o[7] = f2bf(b[3]);
        ((u16x8*)xb)[i] = o;
    }
}

// One block: 32 rows x 128 output channels. K = 320. LDS = 32*320*2 = 20480 B
// -> 8 blocks/CU. XOR swizzle on 8B chunks: chunk c8 stored at c8 ^ ((row&7)<<1).
// Gather loads carry NT hint (test: L1/MSHR bypass for random single-use rows).
template<bool XB, bool BF16H>
__global__ __launch_bounds__(256, 8) void fused_kernel(
    const float* __restrict__ x, const unsigned short* __restrict__ xb,
    const int* __restrict__ nb,
    const unsigned short* __restrict__ Wb, void* __restrict__ hout,
    float* __restrict__ partials, int E)
{
    __shared__ __align__(16) unsigned short feat[32 * 320];

    const int tid = threadIdx.x;
    const int r0 = blockIdx.x * 32;

    // ---- stage feat tile [x | min01 | max01 | min23 | max23] as bf16, swizzled
    {
        const int lr = tid >> 3;            // local row 0..31
        const int o  = tid & 7;             // 16B chunk within a 64-col section
        const int gr = min(r0 + lr, E - 1);
        int4 nv = *(const int4*)(nb + (long)gr * 4);
        const int i0 = min(max(nv.x, 0), E - 1);
        const int i1 = min(max(nv.y, 0), E - 1);
        const int i2 = min(max(nv.z, 0), E - 1);
        const int i3 = min(max(nv.w, 0), E - 1);
        const int xr = (lr & 7) << 1;
        char* fb = (char*)feat + lr * 640;

        if (XB) {
            const u16x8 xv = __builtin_nontemporal_load((const u16x8*)(xb + (long)gr * 64 + o * 8));
            const u16x8 av = __builtin_nontemporal_load((const u16x8*)(xb + (long)i0 * 64 + o * 8));
            const u16x8 bv = __builtin_nontemporal_load((const u16x8*)(xb + (long)i1 * 64 + o * 8));
            const u16x8 cv = __builtin_nontemporal_load((const u16x8*)(xb + (long)i2 * 64 + o * 8));
            const u16x8 dv = __builtin_nontemporal_load((const u16x8*)(xb + (long)i3 * 64 + o * 8));
            u16x8 lo1, hi1, lo2, hi2;
            #pragma unroll
            for (int e = 0; e < 8; ++e) {
                const bool t1 = bf2f(av[e]) < bf2f(bv[e]);
                lo1[e] = t1 ? av[e] : bv[e];
                hi1[e] = t1 ? bv[e] : av[e];
                const bool t2 = bf2f(cv[e]) < bf2f(dv[e]);
                lo2[e] = t2 ? cv[e] : dv[e];
                hi2[e] = t2 ? dv[e] : cv[e];
            }
            const int c8 = o * 2;
            *(u16x8*)(fb + (((c8 +  0) ^ xr) << 3)) = xv;
            *(u16x8*)(fb + (((c8 + 16) ^ xr) << 3)) = lo1;
            *(u16x8*)(fb + (((c8 + 32) ^ xr) << 3)) = hi1;
            *(u16x8*)(fb + (((c8 + 48) ^ xr) << 3)) = lo2;
            *(u16x8*)(fb + (((c8 + 64) ^ xr) << 3)) = hi2;
        } else {
            #pragma unroll
            for (int c = 0; c < 2; ++c) {
                const int col = o * 8 + c * 4;
                const float4 xvf = *(const float4*)(x + (long)gr * 64 + col);
                const float4 avf = *(const float4*)(x + (long)i0 * 64 + col);
                const float4 bvf = *(const float4*)(x + (long)i1 * 64 + col);
                const float4 cvf = *(const float4*)(x + (long)i2 * 64 + col);
                const float4 dvf = *(const float4*)(x + (long)i3 * 64 + col);
                const float4 vals[5] = { xvf, min4(avf,bvf), max4(avf,bvf),
                                         min4(cvf,dvf), max4(cvf,dvf) };
                #pragma unroll
                for (int s = 0; s < 5; ++s) {
                    const int c8 = s * 16 + o * 2 + c;
                    ushort4 p;
                    p.x = f2bf(vals[s].x); p.y = f2bf(vals[s].y);
                    p.z = f2bf(vals[s].z); p.w = f2bf(vals[s].w);
                    *(ushort4*)(fb + ((c8 ^ xr) << 3)) = p;
                }
            }
        }
    }
    __syncthreads();

    // ---- MFMA: 4 waves; wave w owns cols [w*32, w*32+32). Each: 32 rows x 32 cols.
    const int lane = tid & 63;
    const int wid  = tid >> 6;
    const int lr16 = lane & 15;
    const int lg   = lane >> 4;             // 0..3
    const int xr   = (lr16 & 7) << 1;

    f32x4 acc[2][2];
    #pragma unroll
    for (int m = 0; m < 2; ++m)
        #pragma unroll
        for (int n = 0; n < 2; ++n)
            acc[m][n] = (f32x4){0.f, 0.f, 0.f, 0.f};

    const char* fb0 = (const char*)feat + lr16 * 640;
    const char* fb1 = (const char*)feat + (16 + lr16) * 640;
    const unsigned short* wb = Wb + (wid * 32 + lr16) * 320 + lg * 8;

    #pragma unroll
    for (int kk = 0; kk < 320; kk += 32) {
        const int c8  = (kk >> 2) + lg * 2;
        const int off = (c8 ^ xr) << 3;
        const short8 a0 = *(const short8*)(fb0 + off);
        const short8 a1 = *(const short8*)(fb1 + off);
        const short8 b0 = *(const short8*)(wb + kk);
        const short8 b1 = *(const short8*)(wb + 16 * 320 + kk);
        acc[0][0] = __builtin_amdgcn_mfma_f32_16x16x32_bf16(a0, b0, acc[0][0], 0, 0, 0);
        acc[0][1] = __builtin_amdgcn_mfma_f32_16x16x32_bf16(a0, b1, acc[0][1], 0, 0, 0);
        acc[1][0] = __builtin_amdgcn_mfma_f32_16x16x32_bf16(a1, b0, acc[1][0], 0, 0, 0);
        acc[1][1] = __builtin_amdgcn_mfma_f32_16x16x32_bf16(a1, b1, acc[1][1], 0, 0, 0);
    }

    // ---- stats from regs (D layout: col = lane&15, row = (lane>>4)*4 + reg)
    #pragma unroll
    for (int n = 0; n < 2; ++n) {
        const int col = wid * 32 + n * 16 + lr16;
        float s = 0.f, q = 0.f;
        #pragma unroll
        for (int m = 0; m < 2; ++m) {
            const int rbase = r0 + m * 16 + lg * 4;
            #pragma unroll
            for (int j = 0; j < 4; ++j) {
                if (rbase + j < E) {
                    const float v = acc[m][n][j];
                    s += v;
                    q += v * v;
                }
            }
        }
        s += __shfl_xor(s, 16); s += __shfl_xor(s, 32);
        q += __shfl_xor(q, 16); q += __shfl_xor(q, 32);
        if (lg == 0) {
            float* base = partials + (blockIdx.x & 63) * 256;
            atomicAdd(&base[col], s);
            atomicAdd(&base[128 + col], q);
        }
    }

    if (BF16H) {
        // ---- transpose acc through LDS (reuse feat), then coalesced NT 16B stores
        __syncthreads();                      // all waves done reading feat
        unsigned short* hsm = feat;           // 32 rows x pitch 132
        #pragma unroll
        for (int m = 0; m < 2; ++m) {
            const int rb = m * 16 + lg * 4;
            #pragma unroll
            for (int n = 0; n < 2; ++n) {
                const int col = wid * 32 + n * 16 + lr16;
                #pragma unroll
                for (int j = 0; j < 4; ++j)
                    hsm[(rb + j) * 132 + col] = f2bf(acc[m][n][j]);
            }
        }
        __syncthreads();
        unsigned short* hb = (unsigned short*)hout;
        const int oct = tid & 15;             // 8-col chunk
        const int lrr = tid >> 4;             // 0..15
        #pragma unroll
        for (int it = 0; it < 2; ++it) {
            const int r = lrr + it * 16;
            const int grow = r0 + r;
            if (grow < E)
                __builtin_nontemporal_store(
                    *(const u16x8*)(hsm + r * 132 + oct * 8),
                    (u16x8*)(hb + (long)grow * 128 + oct * 8));
        }
    } else {
        float* hf = (float*)hout;
        #pragma unroll
        for (int n = 0; n < 2; ++n) {
            const int col = wid * 32 + n * 16 + lr16;
            #pragma unroll
            for (int m = 0; m < 2; ++m) {
                const int rbase = r0 + m * 16 + lg * 4;
                #pragma unroll
                for (int j = 0; j < 4; ++j) {
                    const int grow = rbase + j;
                    if (grow < E)
                        __builtin_nontemporal_store(acc[m][n][j],
                            hf + (long)grow * 128 + col);
                }
            }
        }
    }
}

__global__ void finalize_kernel(const float* __restrict__ partials,
                                const float* __restrict__ gamma,
                                const float* __restrict__ beta,
                                float* __restrict__ sb, int E)
{
    const int c = threadIdx.x;   // 0..127
    float s = 0.f, q = 0.f;
    for (int b = 0; b < 64; ++b) {
        s += partials[b * 256 + c];
        q += partials[b * 256 + 128 + c];
    }
    const float inv  = 1.0f / (float)E;
    const float mean = s * inv;
    const float var  = fmaxf(q * inv - mean * mean, 0.f);
    const float sc   = gamma[c] / sqrtf(var + 1e-5f);
    sb[c]       = sc;
    sb[128 + c] = beta[c] - mean * sc;
}

// bf16-h: one f32x4 chunk per thread per iter. 8B NT load (512B/instr/wave),
// 16B NT store (1KB/instr/wave) -> full coalescing density both directions.
__global__ __launch_bounds__(256) void bn_relu_bf16_kernel(
    const unsigned short* __restrict__ hb, const float* __restrict__ sb,
    float* __restrict__ out, long n4)
{
    __shared__ float s_s[128], s_b[128];
    if (threadIdx.x < 128) {
        s_s[threadIdx.x] = sb[threadIdx.x];
        s_b[threadIdx.x] = sb[128 + threadIdx.x];
    }
    __syncthreads();
    long j = blockIdx.x * 256L + threadIdx.x;
    const long stride = gridDim.x * 256L;
    for (; j < n4; j += stride) {
        const u16x4 v = __builtin_nontemporal_load(((const u16x4*)hb) + j);
        const int c0 = ((int)j & 31) << 2;
        f32x4 o;
        o[0] = fmaxf(fmaf(bf2f(v[0]), s_s[c0+0], s_b[c0+0]), 0.f);
        o[1] = fmaxf(fmaf(bf2f(v[1]), s_s[c0+1], s_b[c0+1]), 0.f);
        o[2] = fmaxf(fmaf(bf2f(v[2]), s_s[c0+2], s_b[c0+2]), 0.f);
        o[3] = fmaxf(fmaf(bf2f(v[3]), s_s[c0+3], s_b[c0+3]), 0.f);
        __builtin_nontemporal_store(o, ((f32x4*)out) + j);
    }
}

// f32 fallback: in-place on d_out
__global__ __launch_bounds__(256) void bn_relu_kernel(float* __restrict__ h,
                                                      const float* __restrict__ sb, long n4)
{
    __shared__ float s_s[128], s_b[128];
    if (threadIdx.x < 128) {
        s_s[threadIdx.x] = sb[threadIdx.x];
        s_b[threadIdx.x] = sb[128 + threadIdx.x];
    }
    __syncthreads();
    long i = blockIdx.x * 256L + threadIdx.x;
    const long stride = gridDim.x * 256L;
    for (; i < n4; i += stride) {
        f32x4 v = __builtin_nontemporal_load(((const f32x4*)h) + i);
        const int c = ((int)i * 4) & 127;
        v[0] = fmaxf(fmaf(v[0], s_s[c + 0], s_b[c + 0]), 0.f);
        v[1] = fmaxf(fmaf(v[1], s_s[c + 1], s_b[c + 1]), 0.f);
        v[2] = fmaxf(fmaf(v[2], s_s[c + 2], s_b[c + 2]), 0.f);
        v[3] = fmaxf(fmaf(v[3], s_s[c + 3], s_b[c + 3]), 0.f);
        __builtin_nontemporal_store(v, ((f32x4*)h) + i);
    }
}

extern "C" void kernel_launch(void* const* d_in, const int* in_sizes, int n_in,
                              void* d_out, int out_size, void* d_ws, size_t ws_size,
                              hipStream_t stream)
{
    const float* x     = (const float*)d_in[0];
    const int*   nb    = (const int*)d_in[1];
    const float* W     = (const float*)d_in[2];
    const float* gamma = (const float*)d_in[3];
    const float* beta  = (const float*)d_in[4];
    float* out = (float*)d_out;

    const int E = in_sizes[0] / 64;

    // ws layout: Wb 80K | partials 64K | sb 1K | xb (E*128 B) | hb (E*256 B)
    char* ws = (char*)d_ws;
    unsigned short* Wb       = (unsigned short*)ws;
    float*          partials = (float*)(ws + 81920);
    float*          sb       = (float*)(ws + 81920 + 65536);
    unsigned short* xb       = (unsigned short*)(ws + 148480);
    const size_t xb_end = 148480 + (size_t)E * 128;
    unsigned short* hb       = (unsigned short*)(ws + xb_end);
    const bool have_xb = (ws_size >= xb_end);
    const bool have_hb = (ws_size >= xb_end + (size_t)E * 256);

    if (have_xb)
        prep_conv_kernel<<<2048, 256, 0, stream>>>(W, Wb, partials, x, xb, (long)E * 8);
    else
        prep_kernel<<<160, 256, 0, stream>>>(W, Wb, partials);

    const int T = (E + 31) / 32;
    void* hdst = have_hb ? (void*)hb : (void*)out;
    if (have_xb && have_hb)
        fused_kernel<true,  true ><<<T, 256, 0, stream>>>(x, xb, nb, Wb, hdst, partials, E);
    else if (have_xb)
        fused_kernel<true,  false><<<T, 256, 0, stream>>>(x, xb, nb, Wb, hdst, partials, E);
    else if (have_hb)
        fused_kernel<false, true ><<<T, 256, 0, stream>>>(x, xb, nb, Wb, hdst, partials, E);
    else
        fused_kernel<false, false><<<T, 256, 0, stream>>>(x, xb, nb, Wb, hdst, partials, E);

    finalize_kernel<<<1, 128, 0, stream>>>(partials, gamma, beta, sb, E);

    if (have_hb)
        bn_relu_bf16_kernel<<<4096, 256, 0, stream>>>(hb, sb, out, (long)E * 32);
    else
        bn_relu_kernel<<<2048, 256, 0, stream>>>(out, sb, (long)E * 32);
}

// Round 11
// 269.208 us; speedup vs baseline: 1.8573x; 1.1316x over previous
//
#include <hip/hip_runtime.h>
#include <hip/hip_bf16.h>

typedef __attribute__((ext_vector_type(8))) short short8;
typedef __attribute__((ext_vector_type(8))) unsigned short u16x8;
typedef __attribute__((ext_vector_type(4))) unsigned short u16x4;
typedef __attribute__((ext_vector_type(4))) float f32x4;

__device__ __forceinline__ unsigned short f2bf(float f) {
    unsigned int u = __float_as_uint(f);
    unsigned int r = (u + 0x7fffu + ((u >> 16) & 1u)) >> 16;   // RNE
    return (unsigned short)r;
}
__device__ __forceinline__ float bf2f(unsigned short u) {
    return __uint_as_float(((unsigned int)u) << 16);
}
__device__ __forceinline__ float4 min4(float4 a, float4 b) {
    return make_float4(fminf(a.x,b.x), fminf(a.y,b.y), fminf(a.z,b.z), fminf(a.w,b.w));
}
__device__ __forceinline__ float4 max4(float4 a, float4 b) {
    return make_float4(fmaxf(a.x,b.x), fmaxf(a.y,b.y), fmaxf(a.z,b.z), fmaxf(a.w,b.w));
}

// fallback-only: zero stat partials + convert W to bf16
__global__ __launch_bounds__(256) void prep_kernel(const float* __restrict__ W,
                                                   unsigned short* __restrict__ Wb,
                                                   float* __restrict__ partials) {
    const int i = blockIdx.x * 256 + threadIdx.x;
    if (i < 64 * 256) partials[i] = 0.f;
    if (i < 128 * 320) Wb[i] = f2bf(W[i]);
}

// zero partials + W->bf16 + x->bf16 (one launch)
__global__ __launch_bounds__(256) void prep_conv_kernel(
    const float* __restrict__ W, unsigned short* __restrict__ Wb,
    float* __restrict__ partials,
    const float* __restrict__ x, unsigned short* __restrict__ xb, long n8)
{
    const long g = blockIdx.x * 256L + threadIdx.x;
    if (g < 64 * 256) partials[g] = 0.f;
    if (g < 128 * 320) Wb[g] = f2bf(W[g]);
    const long stride = gridDim.x * 256L;
    for (long i = g; i < n8; i += stride) {
        const f32x4 a = __builtin_nontemporal_load(((const f32x4*)x) + i * 2);
        const f32x4 b = __builtin_nontemporal_load(((const f32x4*)x) + i * 2 + 1);
        u16x8 o;
        o[0] = f2bf(a[0]); o[1] = f2bf(a[1]); o[2] = f2bf(a[2]); o[3] = f2bf(a[3]);
        o[4] = f2bf(b[0]); o[5] = f2bf(b[1]); o[6] = f2bf(b[2]); o[7] = f2bf(b[3]);
        ((u16x8*)xb)[i] = o;
    }
}

// One block: 32 rows x 128 output channels. K = 320. LDS = 32*320*2 = 20480 B
// -> 8 blocks/CU. XOR swizzle on 8B chunks: chunk c8 stored at c8 ^ ((row&7)<<1).
// Gather loads are PLAIN CACHED (NT hurt: ~half the random rows L2-hit; R10).
template<bool XB, bool BF16H>
__global__ __launch_bounds__(256, 8) void fused_kernel(
    const float* __restrict__ x, const unsigned short* __restrict__ xb,
    const int* __restrict__ nb,
    const unsigned short* __restrict__ Wb, void* __restrict__ hout,
    float* __restrict__ partials, int E)
{
    __shared__ __align__(16) unsigned short feat[32 * 320];

    const int tid = threadIdx.x;
    const int r0 = blockIdx.x * 32;

    // ---- stage feat tile [x | min01 | max01 | min23 | max23] as bf16, swizzled
    {
        const int lr = tid >> 3;            // local row 0..31
        const int o  = tid & 7;             // 16B chunk within a 64-col section
        const int gr = min(r0 + lr, E - 1);
        int4 nv = *(const int4*)(nb + (long)gr * 4);
        const int i0 = min(max(nv.x, 0), E - 1);
        const int i1 = min(max(nv.y, 0), E - 1);
        const int i2 = min(max(nv.z, 0), E - 1);
        const int i3 = min(max(nv.w, 0), E - 1);
        const int xr = (lr & 7) << 1;
        char* fb = (char*)feat + lr * 640;

        if (XB) {
            const u16x8 xv = *(const u16x8*)(xb + (long)gr * 64 + o * 8);
            const u16x8 av = *(const u16x8*)(xb + (long)i0 * 64 + o * 8);
            const u16x8 bv = *(const u16x8*)(xb + (long)i1 * 64 + o * 8);
            const u16x8 cv = *(const u16x8*)(xb + (long)i2 * 64 + o * 8);
            const u16x8 dv = *(const u16x8*)(xb + (long)i3 * 64 + o * 8);
            u16x8 lo1, hi1, lo2, hi2;
            #pragma unroll
            for (int e = 0; e < 8; ++e) {
                const bool t1 = bf2f(av[e]) < bf2f(bv[e]);
                lo1[e] = t1 ? av[e] : bv[e];
                hi1[e] = t1 ? bv[e] : av[e];
                const bool t2 = bf2f(cv[e]) < bf2f(dv[e]);
                lo2[e] = t2 ? cv[e] : dv[e];
                hi2[e] = t2 ? dv[e] : cv[e];
            }
            const int c8 = o * 2;
            *(u16x8*)(fb + (((c8 +  0) ^ xr) << 3)) = xv;
            *(u16x8*)(fb + (((c8 + 16) ^ xr) << 3)) = lo1;
            *(u16x8*)(fb + (((c8 + 32) ^ xr) << 3)) = hi1;
            *(u16x8*)(fb + (((c8 + 48) ^ xr) << 3)) = lo2;
            *(u16x8*)(fb + (((c8 + 64) ^ xr) << 3)) = hi2;
        } else {
            #pragma unroll
            for (int c = 0; c < 2; ++c) {
                const int col = o * 8 + c * 4;
                const float4 xvf = *(const float4*)(x + (long)gr * 64 + col);
                const float4 avf = *(const float4*)(x + (long)i0 * 64 + col);
                const float4 bvf = *(const float4*)(x + (long)i1 * 64 + col);
                const float4 cvf = *(const float4*)(x + (long)i2 * 64 + col);
                const float4 dvf = *(const float4*)(x + (long)i3 * 64 + col);
                const float4 vals[5] = { xvf, min4(avf,bvf), max4(avf,bvf),
                                         min4(cvf,dvf), max4(cvf,dvf) };
                #pragma unroll
                for (int s = 0; s < 5; ++s) {
                    const int c8 = s * 16 + o * 2 + c;
                    ushort4 p;
                    p.x = f2bf(vals[s].x); p.y = f2bf(vals[s].y);
                    p.z = f2bf(vals[s].z); p.w = f2bf(vals[s].w);
                    *(ushort4*)(fb + ((c8 ^ xr) << 3)) = p;
                }
            }
        }
    }
    __syncthreads();

    // ---- MFMA: 4 waves; wave w owns cols [w*32, w*32+32). Each: 32 rows x 32 cols.
    const int lane = tid & 63;
    const int wid  = tid >> 6;
    const int lr16 = lane & 15;
    const int lg   = lane >> 4;             // 0..3
    const int xr   = (lr16 & 7) << 1;

    f32x4 acc[2][2];
    #pragma unroll
    for (int m = 0; m < 2; ++m)
        #pragma unroll
        for (int n = 0; n < 2; ++n)
            acc[m][n] = (f32x4){0.f, 0.f, 0.f, 0.f};

    const char* fb0 = (const char*)feat + lr16 * 640;
    const char* fb1 = (const char*)feat + (16 + lr16) * 640;
    const unsigned short* wb = Wb + (wid * 32 + lr16) * 320 + lg * 8;

    #pragma unroll
    for (int kk = 0; kk < 320; kk += 32) {
        const int c8  = (kk >> 2) + lg * 2;
        const int off = (c8 ^ xr) << 3;
        const short8 a0 = *(const short8*)(fb0 + off);
        const short8 a1 = *(const short8*)(fb1 + off);
        const short8 b0 = *(const short8*)(wb + kk);
        const short8 b1 = *(const short8*)(wb + 16 * 320 + kk);
        acc[0][0] = __builtin_amdgcn_mfma_f32_16x16x32_bf16(a0, b0, acc[0][0], 0, 0, 0);
        acc[0][1] = __builtin_amdgcn_mfma_f32_16x16x32_bf16(a0, b1, acc[0][1], 0, 0, 0);
        acc[1][0] = __builtin_amdgcn_mfma_f32_16x16x32_bf16(a1, b0, acc[1][0], 0, 0, 0);
        acc[1][1] = __builtin_amdgcn_mfma_f32_16x16x32_bf16(a1, b1, acc[1][1], 0, 0, 0);
    }

    // ---- stats from regs (D layout: col = lane&15, row = (lane>>4)*4 + reg)
    #pragma unroll
    for (int n = 0; n < 2; ++n) {
        const int col = wid * 32 + n * 16 + lr16;
        float s = 0.f, q = 0.f;
        #pragma unroll
        for (int m = 0; m < 2; ++m) {
            const int rbase = r0 + m * 16 + lg * 4;
            #pragma unroll
            for (int j = 0; j < 4; ++j) {
                if (rbase + j < E) {
                    const float v = acc[m][n][j];
                    s += v;
                    q += v * v;
                }
            }
        }
        s += __shfl_xor(s, 16); s += __shfl_xor(s, 32);
        q += __shfl_xor(q, 16); q += __shfl_xor(q, 32);
        if (lg == 0) {
            float* base = partials + (blockIdx.x & 63) * 256;
            atomicAdd(&base[col], s);
            atomicAdd(&base[128 + col], q);
        }
    }

    if (BF16H) {
        // ---- transpose acc through LDS (reuse feat), then coalesced NT 16B stores
        __syncthreads();                      // all waves done reading feat
        unsigned short* hsm = feat;           // 32 rows x pitch 132
        #pragma unroll
        for (int m = 0; m < 2; ++m) {
            const int rb = m * 16 + lg * 4;
            #pragma unroll
            for (int n = 0; n < 2; ++n) {
                const int col = wid * 32 + n * 16 + lr16;
                #pragma unroll
                for (int j = 0; j < 4; ++j)
                    hsm[(rb + j) * 132 + col] = f2bf(acc[m][n][j]);
            }
        }
        __syncthreads();
        unsigned short* hb = (unsigned short*)hout;
        const int oct = tid & 15;             // 8-col chunk
        const int lrr = tid >> 4;             // 0..15
        #pragma unroll
        for (int it = 0; it < 2; ++it) {
            const int r = lrr + it * 16;
            const int grow = r0 + r;
            if (grow < E)
                __builtin_nontemporal_store(
                    *(const u16x8*)(hsm + r * 132 + oct * 8),
                    (u16x8*)(hb + (long)grow * 128 + oct * 8));
        }
    } else {
        float* hf = (float*)hout;
        #pragma unroll
        for (int n = 0; n < 2; ++n) {
            const int col = wid * 32 + n * 16 + lr16;
            #pragma unroll
            for (int m = 0; m < 2; ++m) {
                const int rbase = r0 + m * 16 + lg * 4;
                #pragma unroll
                for (int j = 0; j < 4; ++j) {
                    const int grow = rbase + j;
                    if (grow < E)
                        __builtin_nontemporal_store(acc[m][n][j],
                            hf + (long)grow * 128 + col);
                }
            }
        }
    }
}

__global__ void finalize_kernel(const float* __restrict__ partials,
                                const float* __restrict__ gamma,
                                const float* __restrict__ beta,
                                float* __restrict__ sb, int E)
{
    const int c = threadIdx.x;   // 0..127
    float s = 0.f, q = 0.f;
    for (int b = 0; b < 64; ++b) {
        s += partials[b * 256 + c];
        q += partials[b * 256 + 128 + c];
    }
    const float inv  = 1.0f / (float)E;
    const float mean = s * inv;
    const float var  = fmaxf(q * inv - mean * mean, 0.f);
    const float sc   = gamma[c] / sqrtf(var + 1e-5f);
    sb[c]       = sc;
    sb[128 + c] = beta[c] - mean * sc;
}

// bf16-h: one f32x4 chunk per thread per iter. 8B NT load (512B/instr/wave),
// 16B NT store (1KB/instr/wave) -> full coalescing density both directions.
__global__ __launch_bounds__(256) void bn_relu_bf16_kernel(
    const unsigned short* __restrict__ hb, const float* __restrict__ sb,
    float* __restrict__ out, long n4)
{
    __shared__ float s_s[128], s_b[128];
    if (threadIdx.x < 128) {
        s_s[threadIdx.x] = sb[threadIdx.x];
        s_b[threadIdx.x] = sb[128 + threadIdx.x];
    }
    __syncthreads();
    long j = blockIdx.x * 256L + threadIdx.x;
    const long stride = gridDim.x * 256L;
    for (; j < n4; j += stride) {
        const u16x4 v = __builtin_nontemporal_load(((const u16x4*)hb) + j);
        const int c0 = ((int)j & 31) << 2;
        f32x4 o;
        o[0] = fmaxf(fmaf(bf2f(v[0]), s_s[c0+0], s_b[c0+0]), 0.f);
        o[1] = fmaxf(fmaf(bf2f(v[1]), s_s[c0+1], s_b[c0+1]), 0.f);
        o[2] = fmaxf(fmaf(bf2f(v[2]), s_s[c0+2], s_b[c0+2]), 0.f);
        o[3] = fmaxf(fmaf(bf2f(v[3]), s_s[c0+3], s_b[c0+3]), 0.f);
        __builtin_nontemporal_store(o, ((f32x4*)out) + j);
    }
}

// f32 fallback: in-place on d_out
__global__ __launch_bounds__(256) void bn_relu_kernel(float* __restrict__ h,
                                                      const float* __restrict__ sb, long n4)
{
    __shared__ float s_s[128], s_b[128];
    if (threadIdx.x < 128) {
        s_s[threadIdx.x] = sb[threadIdx.x];
        s_b[threadIdx.x] = sb[128 + threadIdx.x];
    }
    __syncthreads();
    long i = blockIdx.x * 256L + threadIdx.x;
    const long stride = gridDim.x * 256L;
    for (; i < n4; i += stride) {
        f32x4 v = __builtin_nontemporal_load(((const f32x4*)h) + i);
        const int c = ((int)i * 4) & 127;
        v[0] = fmaxf(fmaf(v[0], s_s[c + 0], s_b[c + 0]), 0.f);
        v[1] = fmaxf(fmaf(v[1], s_s[c + 1], s_b[c + 1]), 0.f);
        v[2] = fmaxf(fmaf(v[2], s_s[c + 2], s_b[c + 2]), 0.f);
        v[3] = fmaxf(fmaf(v[3], s_s[c + 3], s_b[c + 3]), 0.f);
        __builtin_nontemporal_store(v, ((f32x4*)h) + i);
    }
}

extern "C" void kernel_launch(void* const* d_in, const int* in_sizes, int n_in,
                              void* d_out, int out_size, void* d_ws, size_t ws_size,
                              hipStream_t stream)
{
    const float* x     = (const float*)d_in[0];
    const int*   nb    = (const int*)d_in[1];
    const float* W     = (const float*)d_in[2];
    const float* gamma = (const float*)d_in[3];
    const float* beta  = (const float*)d_in[4];
    float* out = (float*)d_out;

    const int E = in_sizes[0] / 64;

    // ws layout: Wb 80K | partials 64K | sb 1K | xb (E*128 B) | hb (E*256 B)
    char* ws = (char*)d_ws;
    unsigned short* Wb       = (unsigned short*)ws;
    float*          partials = (float*)(ws + 81920);
    float*          sb       = (float*)(ws + 81920 + 65536);
    unsigned short* xb       = (unsigned short*)(ws + 148480);
    const size_t xb_end = 148480 + (size_t)E * 128;
    unsigned short* hb       = (unsigned short*)(ws + xb_end);
    const bool have_xb = (ws_size >= xb_end);
    const bool have_hb = (ws_size >= xb_end + (size_t)E * 256);

    if (have_xb)
        prep_conv_kernel<<<2048, 256, 0, stream>>>(W, Wb, partials, x, xb, (long)E * 8);
    else
        prep_kernel<<<160, 256, 0, stream>>>(W, Wb, partials);

    const int T = (E + 31) / 32;
    void* hdst = have_hb ? (void*)hb : (void*)out;
    if (have_xb && have_hb)
        fused_kernel<true,  true ><<<T, 256, 0, stream>>>(x, xb, nb, Wb, hdst, partials, E);
    else if (have_xb)
        fused_kernel<true,  false><<<T, 256, 0, stream>>>(x, xb, nb, Wb, hdst, partials, E);
    else if (have_hb)
        fused_kernel<false, true ><<<T, 256, 0, stream>>>(x, xb, nb, Wb, hdst, partials, E);
    else
        fused_kernel<false, false><<<T, 256, 0, stream>>>(x, xb, nb, Wb, hdst, partials, E);

    finalize_kernel<<<1, 128, 0, stream>>>(partials, gamma, beta, sb, E);

    if (have_hb)
        bn_relu_bf16_kernel<<<4096, 256, 0, stream>>>(hb, sb, out, (long)E * 32);
    else
        bn_relu_kernel<<<2048, 256, 0, stream>>>(out, sb, (long)E * 32);
}